// Round 10
// baseline (110.514 us; speedup 1.0000x reference)
//
#include <hip/hip_runtime.h>
#include <math.h>

// RingConv2d = atan2( sum sin(x-w), sum cos(x-w) ) over 3x3xC patches.
//   cos(x-w) = cx*cw + sx*sw ; sin(x-w) = sx*cw - cx*sw   (ringify is a no-op)
// All-f32 fmaf path (proven absmax 0.00195 in rounds 1/2/5).
// Single fused kernel:
//  - per-block weight trig table in LDS, read as broadcast ds_read_b128
//    (uniform address -> no SGPR pressure, no scalar-load stalls)
//  - pixel sincos computed inline during LDS staging (no workspace at all)
//  - OC=4 outputs/thread amortizes pixel LDS reads (halves bytes/output vs OC=2)

typedef float f32x2 __attribute__((ext_vector_type(2)));
typedef float f32x4 __attribute__((ext_vector_type(4)));

#define B_   4
#define C_   32
#define H_   64
#define W_   64
#define O_   64
#define OC   4            // output channels per thread
#define NOG  (O_ / OC)    // 16 o-groups
#define CG   8            // input channels per LDS stage
#define HW   (H_ * W_)

__global__ __launch_bounds__(256, 4) void ring_fused(const float* __restrict__ x,
                                                     const float* __restrict__ w,
                                                     float* __restrict__ out) {
    // pixel tile: (cos,sin) f32 pairs
    __shared__ f32x2 sm[CG][18][18];              // 20736 B
    // weight table: [c][ij][pair] = {cw(2p),sw(2p),cw(2p+1),sw(2p+1)}
    __shared__ f32x4 wsm[C_][9][OC / 2];          // 9216 B   (total 29952 B)

    const int tid = threadIdx.x;
    const int tile = blockIdx.x;            // 16 tiles of 16x16
    const int tile_y = (tile >> 2) * 16;
    const int tile_x = (tile & 3) * 16;
    const int ob = blockIdx.y * OC;         // o-group base
    const int b  = blockIdx.z;

    // ---- one-time weight trig: C*9*OC = 1152 items, 4.5 per thread
#pragma unroll 1
    for (int i = tid; i < C_ * 9 * OC; i += 256) {
        int c    = i / (9 * OC);
        int rest = i % (9 * OC);
        int ij   = rest >> 2;               // OC = 4
        int oo   = rest & 3;
        float wv = w[(ob + oo) * (C_ * 9) + c * 9 + ij];
        float s, cc;
        __sincosf(wv, &s, &cc);
        float* dst = (float*)&wsm[c][ij][oo >> 1];
        dst[(oo & 1) * 2 + 0] = cc;
        dst[(oo & 1) * 2 + 1] = s;
    }
    // first __syncthreads below fences the weight table

    const int ty = tid >> 4;                // 0..15
    const int tx = tid & 15;                // 0..15

    float ax[OC], ay[OC];
#pragma unroll
    for (int o = 0; o < OC; ++o) { ax[o] = 0.f; ay[o] = 0.f; }

    const float* xb = x + (size_t)b * C_ * HW;

    for (int cg = 0; cg < C_; cg += CG) {
        __syncthreads();
        // stage CG x 18 x 18 (cos,sin); zero-pad halo -> (1,0)
#pragma unroll 1
        for (int c = 0; c < CG; ++c) {
#pragma unroll 1
            for (int i = tid; i < 324; i += 256) {
                int r  = i / 18;
                int cl = i % 18;
                int hh = tile_y + r - 1;
                int ww = tile_x + cl - 1;
                f32x2 v = (f32x2){1.f, 0.f};
                if ((unsigned)hh < (unsigned)H_ && (unsigned)ww < (unsigned)W_) {
                    float s, cc;
                    __sincosf(xb[(cg + c) * HW + hh * W_ + ww], &s, &cc);
                    v = (f32x2){cc, s};
                }
                sm[c][r][cl] = v;
            }
        }
        __syncthreads();

#pragma unroll 2
        for (int c = 0; c < CG; ++c) {
            f32x2 P[9];
#pragma unroll
            for (int i = 0; i < 3; ++i)
#pragma unroll
                for (int j = 0; j < 3; ++j)
                    P[i * 3 + j] = sm[c][ty + i][tx + j];

            const f32x4* wp = &wsm[cg + c][0][0];
#pragma unroll
            for (int ij = 0; ij < 9; ++ij) {
                f32x4 w0 = wp[ij * 2 + 0];      // broadcast ds_read_b128
                f32x4 w1 = wp[ij * 2 + 1];
                float cx = P[ij].x, sx = P[ij].y;
                ax[0] = fmaf(cx, w0.x, fmaf(sx,  w0.y, ax[0]));
                ay[0] = fmaf(sx, w0.x, fmaf(-cx, w0.y, ay[0]));
                ax[1] = fmaf(cx, w0.z, fmaf(sx,  w0.w, ax[1]));
                ay[1] = fmaf(sx, w0.z, fmaf(-cx, w0.w, ay[1]));
                ax[2] = fmaf(cx, w1.x, fmaf(sx,  w1.y, ax[2]));
                ay[2] = fmaf(sx, w1.x, fmaf(-cx, w1.y, ay[2]));
                ax[3] = fmaf(cx, w1.z, fmaf(sx,  w1.w, ax[3]));
                ay[3] = fmaf(sx, w1.z, fmaf(-cx, w1.w, ay[3]));
            }
        }
    }

    const int h  = tile_y + ty;
    const int wc = tile_x + tx;
    float* op = out + (size_t)(b * O_ + ob) * HW + h * W_ + wc;
#pragma unroll
    for (int o = 0; o < OC; ++o)
        op[(size_t)o * HW] = atan2f(ay[o], ax[o]);
}

extern "C" void kernel_launch(void* const* d_in, const int* in_sizes, int n_in,
                              void* d_out, int out_size, void* d_ws, size_t ws_size,
                              hipStream_t stream) {
    const float* x = (const float*)d_in[0];   // (4,32,64,64) f32
    const float* w = (const float*)d_in[1];   // (64,32,3,3)  f32
    float* out = (float*)d_out;               // (4,64,64,64) f32

    dim3 grid((H_ / 16) * (W_ / 16), NOG, B_);
    ring_fused<<<grid, dim3(256), 0, stream>>>(x, w, out);
}

// Round 12
// 75.810 us; speedup vs baseline: 1.4578x; 1.4578x over previous
//
#include <hip/hip_runtime.h>
#include <math.h>

// RingConv2d = atan2( sum sin(x-w), sum cos(x-w) ) over 3x3xC patches.
//   cos(x-w) = cx*cw + sx*sw ; sin(x-w) = sx*cw - cx*sw   (ringify is a no-op)
// Implicit GEMM on MFMA (f16 in, f32 acc):
//   D[m][n] = sum_k A[m][k] B[k][n],  m = pixel (b,h,w),  n<64: ax_o, n>=64: ay_o
//   k = q*2 + t, q = (c*3+i)*4 + j  (j=3 is a DUMMY tap with B=0: pads 9->12
//   taps so each lane's 8 A-elems = 4 consecutive LDS words)
//   A[m][k] = t? sin : cos of x at (h+i-1, w+j-1); halo -> (1,0)
//   B[k][n<64 ] = t? sw : cw ;  B[k][n>=64] = t? cw : -sw
// Frag maps (mfma_f32_16x16x32_f16): A row = lane&15, B col = lane&15,
// k-slot = (lane>>4)*8 + e.  A and B use the SAME slot->k labeling, so the
// dot product is invariant to the HW's internal k order.  C/D: col=lane&15,
// row=(lane>>4)*4+reg (HW-verified mapping).

typedef float f32x4 __attribute__((ext_vector_type(4)));
typedef _Float16 f16;
typedef f16 f16x2 __attribute__((ext_vector_type(2)));
typedef f16 f16x8 __attribute__((ext_vector_type(8)));
typedef unsigned int u32;
typedef u32 u32x4 __attribute__((ext_vector_type(4)));

#define B_   4
#define C_   32
#define H_   64
#define W_   64
#define O_   64
#define HW   (H_ * W_)
#define NPIX (B_ * C_ * HW)                  // 524288
#define KP   24                              // k-steps: K=768 / 32
#define PLANES_BYTES (NPIX * 4)              // 2 MB packed f16 {cos,sin}
#define BSW_ELEMS (8 * KP * 64 * 8)          // 98304 f16 (8 n-frags)
#define BSW_BYTES (BSW_ELEMS * 2)            // 196608
#define NEED_WS ((size_t)PLANES_BYTES + (size_t)BSW_BYTES)

// ---- prep: sincos planes + pre-swizzled B fragments
__global__ __launch_bounds__(256) void ring_prep(const float* __restrict__ x,
                                                 const float* __restrict__ w,
                                                 u32* __restrict__ planes,
                                                 f16* __restrict__ bsw) {
    const int bid = blockIdx.x, tid = threadIdx.x;
    if (bid < 512) {                         // 512*256*4 px = NPIX
        int i = bid * 256 + tid;
        f32x4 xv = ((const f32x4*)x)[i];
        u32x4 pk;
#pragma unroll
        for (int j = 0; j < 4; ++j) {
            float s, cc;
            __sincosf(xv[j], &s, &cc);
            f16x2 h = {(f16)cc, (f16)s};
            pk[j] = __builtin_bit_cast(u32, h);
        }
        ((u32x4*)planes)[i] = pk;
    } else {                                 // 384*256 = 98304 B-elems
        int idx = (bid - 512) * 256 + tid;
        int nf   = idx / 12288;              // n-frag 0..7
        int rem  = idx % 12288;
        int ks   = rem >> 9;                 // 0..23
        int rem2 = rem & 511;
        int lane = rem2 >> 3;
        int e    = rem2 & 7;
        int k = ks * 32 + (lane >> 4) * 8 + e;
        int n = nf * 16 + (lane & 15);
        int q = k >> 1, t = k & 1;
        int j  = q & 3;
        int ri = q >> 2;                     // c*3 + i
        int c  = ri / 3, i3 = ri - 3 * (ri / 3);
        f16 val = (f16)0.f;
        if (j < 3) {
            int o = n & 63;
            float s, cc;
            __sincosf(w[(o * C_ + c) * 9 + i3 * 3 + j], &s, &cc);
            float v = (n < 64) ? (t ? s : cc) : (t ? cc : -s);
            val = (f16)v;
        }
        bsw[idx] = val;
    }
}

// ---- main: one block = 8x8 spatial tile x 32 o's (both ax & ay), 4 waves
__global__ __launch_bounds__(256, 2) void ring_mfma(const u32* __restrict__ planes,
                                                    const f16* __restrict__ bsw,
                                                    float* __restrict__ out) {
    __shared__ u32 sm[C_ * 10 * 12];         // [c][10 rows][12 cols], 15360 B

    const int tid = threadIdx.x;
    const int tile = blockIdx.x;             // 64 tiles of 8x8
    const int TY = (tile >> 3) * 8;
    const int TX = (tile & 7) * 8;
    const int half = blockIdx.y;             // o in [32*half, 32*half+32)
    const int b = blockIdx.z;

    // stage 32 x 10 x 12 packed {cos,sin}; out-of-image -> (1,0)
    const u32* pb = planes + (size_t)b * C_ * HW;
#pragma unroll 1
    for (int i = tid; i < C_ * 120; i += 256) {
        int c  = i / 120;
        int rm = i % 120;
        int rr = rm / 12;
        int cc = rm % 12;
        int gh = TY + rr - 1;
        int gw = TX + cc - 1;
        u32 v = 0x00003C00u;                 // {cos=1h, sin=0h}
        if ((unsigned)gh < (unsigned)H_ && (unsigned)gw < (unsigned)W_)
            v = pb[c * HW + gh * W_ + gw];
        sm[i] = v;
    }
    __syncthreads();

    const int wv = tid >> 6;                 // wave id: M-frag
    const int l  = tid & 63;
    const int g  = l >> 4;                   // k-group
    const int lr = l & 15;                   // A row / B,C col
    const int p  = wv * 16 + lr;             // pixel in 8x8 tile (A row)
    const int py = p >> 3, px = p & 7;

    // n-frag ids: {ax lo, ax hi, ay lo, ay hi} for this half
    const u32x4* bv = (const u32x4*)bsw;
    int ofs0 = (2 * half + 0) * KP * 64 + l;
    int ofs1 = (2 * half + 1) * KP * 64 + l;
    int ofs2 = (4 + 2 * half) * KP * 64 + l;
    int ofs3 = (5 + 2 * half) * KP * 64 + l;

    f32x4 acc0 = {0.f, 0.f, 0.f, 0.f}, acc1 = acc0, acc2 = acc0, acc3 = acc0;

#pragma unroll 2
    for (int ks = 0; ks < KP; ++ks) {
        int ri = ks * 4 + g;                 // c*3 + i, 0..95
        int c  = ri / 3;
        int i3 = ri - 3 * c;
        int base = c * 120 + (py + i3) * 12 + px;
        u32x4 au = {sm[base], sm[base + 1], sm[base + 2], sm[base + 3]};
        f16x8 af = __builtin_bit_cast(f16x8, au);
        f16x8 b0 = __builtin_bit_cast(f16x8, bv[ofs0 + ks * 64]);
        f16x8 b1 = __builtin_bit_cast(f16x8, bv[ofs1 + ks * 64]);
        f16x8 b2 = __builtin_bit_cast(f16x8, bv[ofs2 + ks * 64]);
        f16x8 b3 = __builtin_bit_cast(f16x8, bv[ofs3 + ks * 64]);
        acc0 = __builtin_amdgcn_mfma_f32_16x16x32_f16(af, b0, acc0, 0, 0, 0);
        acc1 = __builtin_amdgcn_mfma_f32_16x16x32_f16(af, b1, acc1, 0, 0, 0);
        acc2 = __builtin_amdgcn_mfma_f32_16x16x32_f16(af, b2, acc2, 0, 0, 0);
        acc3 = __builtin_amdgcn_mfma_f32_16x16x32_f16(af, b3, acc3, 0, 0, 0);
    }

    // epilogue: acc0/1 = ax, acc2/3 = ay (same cols) -> atan2 -> store
#pragma unroll
    for (int r = 0; r < 4; ++r) {
        int p2 = wv * 16 + g * 4 + r;        // C/D row -> pixel
        int h  = TY + (p2 >> 3);
        int wc = TX + (p2 & 7);
        int o0 = half * 32 + lr;
        out[((size_t)(b * O_ + o0) * HW) + h * W_ + wc] = atan2f(acc2[r], acc0[r]);
        out[((size_t)(b * O_ + o0 + 16) * HW) + h * W_ + wc] = atan2f(acc3[r], acc1[r]);
    }
}

// ---- fallback (ws too small): round-10 fused f32 kernel, proven correct
typedef float f32x2 __attribute__((ext_vector_type(2)));
#define FOC 4
#define FCG 8
__global__ __launch_bounds__(256, 4) void ring_fb(const float* __restrict__ x,
                                                  const float* __restrict__ w,
                                                  float* __restrict__ out) {
    __shared__ f32x2 sm2[FCG][18][18];
    __shared__ f32x4 wsm[C_][9][FOC / 2];
    const int tid = threadIdx.x;
    const int tile = blockIdx.x;
    const int tile_y = (tile >> 2) * 16, tile_x = (tile & 3) * 16;
    const int ob = blockIdx.y * FOC;
    const int b = blockIdx.z;
#pragma unroll 1
    for (int i = tid; i < C_ * 9 * FOC; i += 256) {
        int c = i / (9 * FOC), rest = i % (9 * FOC);
        int ij = rest >> 2, oo = rest & 3;
        float s, cc;
        __sincosf(w[(ob + oo) * (C_ * 9) + c * 9 + ij], &s, &cc);
        float* dst = (float*)&wsm[c][ij][oo >> 1];
        dst[(oo & 1) * 2 + 0] = cc;
        dst[(oo & 1) * 2 + 1] = s;
    }
    const int ty = tid >> 4, tx = tid & 15;
    float ax[FOC], ay[FOC];
#pragma unroll
    for (int o = 0; o < FOC; ++o) { ax[o] = 0.f; ay[o] = 0.f; }
    const float* xb = x + (size_t)b * C_ * HW;
    for (int cg = 0; cg < C_; cg += FCG) {
        __syncthreads();
#pragma unroll 1
        for (int i = tid; i < FCG * 324; i += 256) {
            int c = i / 324, rr = i % 324, r = rr / 18, cl = rr % 18;
            int hh = tile_y + r - 1, ww = tile_x + cl - 1;
            f32x2 v = (f32x2){1.f, 0.f};
            if ((unsigned)hh < (unsigned)H_ && (unsigned)ww < (unsigned)W_) {
                float s, cc;
                __sincosf(xb[(cg + c) * HW + hh * W_ + ww], &s, &cc);
                v = (f32x2){cc, s};
            }
            sm2[c][r][cl] = v;
        }
        __syncthreads();
#pragma unroll 2
        for (int c = 0; c < FCG; ++c) {
            f32x2 P[9];
#pragma unroll
            for (int i = 0; i < 3; ++i)
#pragma unroll
                for (int j = 0; j < 3; ++j) P[i * 3 + j] = sm2[c][ty + i][tx + j];
            const f32x4* wp = &wsm[cg + c][0][0];
#pragma unroll
            for (int ij = 0; ij < 9; ++ij) {
                f32x4 w0 = wp[ij * 2 + 0], w1 = wp[ij * 2 + 1];
                float cx = P[ij].x, sx = P[ij].y;
                ax[0] = fmaf(cx, w0.x, fmaf(sx, w0.y, ax[0]));
                ay[0] = fmaf(sx, w0.x, fmaf(-cx, w0.y, ay[0]));
                ax[1] = fmaf(cx, w0.z, fmaf(sx, w0.w, ax[1]));
                ay[1] = fmaf(sx, w0.z, fmaf(-cx, w0.w, ay[1]));
                ax[2] = fmaf(cx, w1.x, fmaf(sx, w1.y, ax[2]));
                ay[2] = fmaf(sx, w1.x, fmaf(-cx, w1.y, ay[2]));
                ax[3] = fmaf(cx, w1.z, fmaf(sx, w1.w, ax[3]));
                ay[3] = fmaf(sx, w1.z, fmaf(-cx, w1.w, ay[3]));
            }
        }
    }
    const int h = tile_y + ty, wc = tile_x + tx;
    float* op = out + (size_t)(b * O_ + ob) * HW + h * W_ + wc;
#pragma unroll
    for (int o = 0; o < FOC; ++o) op[(size_t)o * HW] = atan2f(ay[o], ax[o]);
}

extern "C" void kernel_launch(void* const* d_in, const int* in_sizes, int n_in,
                              void* d_out, int out_size, void* d_ws, size_t ws_size,
                              hipStream_t stream) {
    const float* x = (const float*)d_in[0];   // (4,32,64,64) f32
    const float* w = (const float*)d_in[1];   // (64,32,3,3)  f32
    float* out = (float*)d_out;               // (4,64,64,64) f32

    if (ws_size >= NEED_WS) {
        u32* planes = (u32*)d_ws;
        f16* bsw = (f16*)((char*)d_ws + PLANES_BYTES);
        ring_prep<<<dim3(512 + 384), dim3(256), 0, stream>>>(x, w, planes, bsw);
        dim3 grid(64, 2, B_);
        ring_mfma<<<grid, dim3(256), 0, stream>>>(planes, bsw, out);
    } else {
        dim3 grid(16, O_ / FOC, B_);
        ring_fb<<<grid, dim3(256), 0, stream>>>(x, w, out);
    }
}

// Round 14
// 72.112 us; speedup vs baseline: 1.5325x; 1.0513x over previous
//
#include <hip/hip_runtime.h>
#include <math.h>

// RingConv2d = atan2( sum sin(x-w), sum cos(x-w) ) over 3x3xC patches.
//   cos(x-w) = cx*cw + sx*sw ; sin(x-w) = sx*cw - cx*sw   (ringify is a no-op)
// Implicit GEMM on MFMA (f16 in, f32 acc) — layout VALIDATED in round 12
// (absmax 0.00195):
//   D[m][n] = sum_k A[m][k] B[k][n],  m = pixel,  n<64: ax_o, n>=64: ay_o
//   k = q*2 + t, q = (c*3+i)*4 + j  (j=3 dummy tap, B=0; pads 9->12 taps so
//   each lane's 8 A-elems = 4 consecutive LDS words)
//   B[k][n<64 ] = t? sw : cw ;  B[k][n>=64] = t? cw : -sw
// Round-13 changes (same layout): o split in QUARTERS (16 o/block -> 1024
// blocks, 4 blocks/CU), software-pipelined K loop (prefetch A + B frags),
// LDS planes padded to 128 u32/channel for linear staging.

typedef float f32x4 __attribute__((ext_vector_type(4)));
typedef _Float16 f16;
typedef f16 f16x2 __attribute__((ext_vector_type(2)));
typedef f16 f16x8 __attribute__((ext_vector_type(8)));
typedef unsigned int u32;
typedef u32 u32x4 __attribute__((ext_vector_type(4)));

#define B_   4
#define C_   32
#define H_   64
#define W_   64
#define O_   64
#define HW   (H_ * W_)
#define NPIX (B_ * C_ * HW)                  // 524288
#define KP   24                              // k-steps: K=768 / 32
#define PLANES_BYTES (NPIX * 4)              // 2 MB packed f16 {cos,sin}
#define BSW_ELEMS (8 * KP * 64 * 8)          // 98304 f16 (8 n-frags)
#define BSW_BYTES (BSW_ELEMS * 2)            // 196608
#define NEED_WS ((size_t)PLANES_BYTES + (size_t)BSW_BYTES)

// ---- prep: sincos planes + pre-swizzled B fragments (unchanged from r12)
__global__ __launch_bounds__(256) void ring_prep(const float* __restrict__ x,
                                                 const float* __restrict__ w,
                                                 u32* __restrict__ planes,
                                                 f16* __restrict__ bsw) {
    const int bid = blockIdx.x, tid = threadIdx.x;
    if (bid < 512) {                         // 512*256*4 px = NPIX
        int i = bid * 256 + tid;
        f32x4 xv = ((const f32x4*)x)[i];
        u32x4 pk;
#pragma unroll
        for (int j = 0; j < 4; ++j) {
            float s, cc;
            __sincosf(xv[j], &s, &cc);
            f16x2 h = {(f16)cc, (f16)s};
            pk[j] = __builtin_bit_cast(u32, h);
        }
        ((u32x4*)planes)[i] = pk;
    } else {                                 // 384*256 = 98304 B-elems
        int idx = (bid - 512) * 256 + tid;
        int nf   = idx / 12288;              // n-frag 0..7
        int rem  = idx % 12288;
        int ks   = rem >> 9;                 // 0..23
        int rem2 = rem & 511;
        int lane = rem2 >> 3;
        int e    = rem2 & 7;
        int k = ks * 32 + (lane >> 4) * 8 + e;
        int n = nf * 16 + (lane & 15);
        int q = k >> 1, t = k & 1;
        int j  = q & 3;
        int ri = q >> 2;                     // c*3 + i
        int c  = ri / 3, i3 = ri - 3 * (ri / 3);
        f16 val = (f16)0.f;
        if (j < 3) {
            int o = n & 63;
            float s, cc;
            __sincosf(w[(o * C_ + c) * 9 + i3 * 3 + j], &s, &cc);
            float v = (n < 64) ? (t ? s : cc) : (t ? cc : -s);
            val = (f16)v;
        }
        bsw[idx] = val;
    }
}

// ---- main: one block = 8x8 spatial tile x 16 o's (ax & ay), 4 waves
__global__ __launch_bounds__(256, 4) void ring_mfma(const u32* __restrict__ planes,
                                                    const f16* __restrict__ bsw,
                                                    float* __restrict__ out) {
    __shared__ u32 sm[C_ * 128];             // [c][128] (120 used), 16384 B

    const int tid = threadIdx.x;
    const int tile = blockIdx.x;             // 64 tiles of 8x8
    const int TY = (tile >> 3) * 8;
    const int TX = (tile & 7) * 8;
    const int q4 = blockIdx.y;               // o-quarter: o in [16q4, 16q4+16)
    const int b = blockIdx.z;

    // stage 32 x 10 x 12 packed {cos,sin}, linear index (row pad 120->128)
    const u32* pb = planes + (size_t)b * C_ * HW;
#pragma unroll 1
    for (int it = 0; it < 16; ++it) {
        int i  = it * 256 + tid;
        int rm = i & 127;
        u32 v = 0x00003C00u;                 // {cos=1h, sin=0h}
        if (rm < 120) {
            int c  = i >> 7;
            int rr = rm / 12;
            int cl = rm - rr * 12;
            int gh = TY + rr - 1;
            int gw = TX + cl - 1;
            if ((unsigned)gh < (unsigned)H_ && (unsigned)gw < (unsigned)W_)
                v = pb[c * HW + gh * W_ + gw];
        }
        sm[i] = v;
    }
    __syncthreads();

    const int wv = tid >> 6;                 // wave id: M-frag
    const int l  = tid & 63;
    const int g  = l >> 4;                   // k-group
    const int lr = l & 15;                   // A row / B,C col
    const int p  = wv * 16 + lr;             // pixel in 8x8 tile (A row)
    const int py12 = (p >> 3) * 12;
    const int px = p & 7;

    const u32x4* bv = (const u32x4*)bsw;
    const int ofs0 = q4 * (KP * 64) + l;         // ax n-frag
    const int ofs1 = (4 + q4) * (KP * 64) + l;   // ay n-frag

    f32x4 acc0 = {0.f, 0.f, 0.f, 0.f}, acc1 = acc0;

    // software-pipelined K loop (prefetch next A-quad + B-frags)
    auto ldA = [&](int ks) -> u32x4 {
        int ri = ks * 4 + g;                 // c*3 + i, 0..95
        int c  = ri / 3;
        int i3 = ri - 3 * c;
        int base = (c << 7) + py12 + i3 * 12 + px;
        return (u32x4){sm[base], sm[base + 1], sm[base + 2], sm[base + 3]};
    };

    u32x4 a_c = ldA(0);
    u32x4 b0_c = bv[ofs0];
    u32x4 b1_c = bv[ofs1];

#pragma unroll 4
    for (int ks = 0; ks < KP; ++ks) {
        int ksn = (ks + 1 < KP) ? ks + 1 : ks;
        u32x4 a_n  = ldA(ksn);
        u32x4 b0_n = bv[ofs0 + ksn * 64];
        u32x4 b1_n = bv[ofs1 + ksn * 64];
        f16x8 af = __builtin_bit_cast(f16x8, a_c);
        acc0 = __builtin_amdgcn_mfma_f32_16x16x32_f16(af, __builtin_bit_cast(f16x8, b0_c), acc0, 0, 0, 0);
        acc1 = __builtin_amdgcn_mfma_f32_16x16x32_f16(af, __builtin_bit_cast(f16x8, b1_c), acc1, 0, 0, 0);
        a_c = a_n; b0_c = b0_n; b1_c = b1_n;
    }

    // epilogue: acc0 = ax, acc1 = ay (col = o = 16q4+lr) -> atan2 -> store
    const int o = q4 * 16 + lr;
    float* ob = out + (size_t)(b * O_ + o) * HW;
#pragma unroll
    for (int r = 0; r < 4; ++r) {
        int p2 = wv * 16 + g * 4 + r;        // C/D row -> pixel
        int h  = TY + (p2 >> 3);
        int wc = TX + (p2 & 7);
        ob[h * W_ + wc] = atan2f(acc1[r], acc0[r]);
    }
}

// ---- fallback (ws too small): round-10 fused f32 kernel, proven correct
typedef float f32x2 __attribute__((ext_vector_type(2)));
#define FOC 4
#define FCG 8
__global__ __launch_bounds__(256, 4) void ring_fb(const float* __restrict__ x,
                                                  const float* __restrict__ w,
                                                  float* __restrict__ out) {
    __shared__ f32x2 sm2[FCG][18][18];
    __shared__ f32x4 wsm[C_][9][FOC / 2];
    const int tid = threadIdx.x;
    const int tile = blockIdx.x;
    const int tile_y = (tile >> 2) * 16, tile_x = (tile & 3) * 16;
    const int ob = blockIdx.y * FOC;
    const int b = blockIdx.z;
#pragma unroll 1
    for (int i = tid; i < C_ * 9 * FOC; i += 256) {
        int c = i / (9 * FOC), rest = i % (9 * FOC);
        int ij = rest >> 2, oo = rest & 3;
        float s, cc;
        __sincosf(w[(ob + oo) * (C_ * 9) + c * 9 + ij], &s, &cc);
        float* dst = (float*)&wsm[c][ij][oo >> 1];
        dst[(oo & 1) * 2 + 0] = cc;
        dst[(oo & 1) * 2 + 1] = s;
    }
    const int ty = tid >> 4, tx = tid & 15;
    float ax[FOC], ay[FOC];
#pragma unroll
    for (int o = 0; o < FOC; ++o) { ax[o] = 0.f; ay[o] = 0.f; }
    const float* xb = x + (size_t)b * C_ * HW;
    for (int cg = 0; cg < C_; cg += FCG) {
        __syncthreads();
#pragma unroll 1
        for (int i = tid; i < FCG * 324; i += 256) {
            int c = i / 324, rr = i % 324, r = rr / 18, cl = rr % 18;
            int hh = tile_y + r - 1, ww = tile_x + cl - 1;
            f32x2 v = (f32x2){1.f, 0.f};
            if ((unsigned)hh < (unsigned)H_ && (unsigned)ww < (unsigned)W_) {
                float s, cc;
                __sincosf(xb[(cg + c) * HW + hh * W_ + ww], &s, &cc);
                v = (f32x2){cc, s};
            }
            sm2[c][r][cl] = v;
        }
        __syncthreads();
#pragma unroll 2
        for (int c = 0; c < FCG; ++c) {
            f32x2 P[9];
#pragma unroll
            for (int i = 0; i < 3; ++i)
#pragma unroll
                for (int j = 0; j < 3; ++j) P[i * 3 + j] = sm2[c][ty + i][tx + j];
            const f32x4* wp = &wsm[cg + c][0][0];
#pragma unroll
            for (int ij = 0; ij < 9; ++ij) {
                f32x4 w0 = wp[ij * 2 + 0], w1 = wp[ij * 2 + 1];
                float cx = P[ij].x, sx = P[ij].y;
                ax[0] = fmaf(cx, w0.x, fmaf(sx, w0.y, ax[0]));
                ay[0] = fmaf(sx, w0.x, fmaf(-cx, w0.y, ay[0]));
                ax[1] = fmaf(cx, w0.z, fmaf(sx, w0.w, ax[1]));
                ay[1] = fmaf(sx, w0.z, fmaf(-cx, w0.w, ay[1]));
                ax[2] = fmaf(cx, w1.x, fmaf(sx, w1.y, ax[2]));
                ay[2] = fmaf(sx, w1.x, fmaf(-cx, w1.y, ay[2]));
                ax[3] = fmaf(cx, w1.z, fmaf(sx, w1.w, ax[3]));
                ay[3] = fmaf(sx, w1.z, fmaf(-cx, w1.w, ay[3]));
            }
        }
    }
    const int h = tile_y + ty, wc = tile_x + tx;
    float* op = out + (size_t)(b * O_ + ob) * HW + h * W_ + wc;
#pragma unroll
    for (int o = 0; o < FOC; ++o) op[(size_t)o * HW] = atan2f(ay[o], ax[o]);
}

extern "C" void kernel_launch(void* const* d_in, const int* in_sizes, int n_in,
                              void* d_out, int out_size, void* d_ws, size_t ws_size,
                              hipStream_t stream) {
    const float* x = (const float*)d_in[0];   // (4,32,64,64) f32
    const float* w = (const float*)d_in[1];   // (64,32,3,3)  f32
    float* out = (float*)d_out;               // (4,64,64,64) f32

    if (ws_size >= NEED_WS) {
        u32* planes = (u32*)d_ws;
        f16* bsw = (f16*)((char*)d_ws + PLANES_BYTES);
        ring_prep<<<dim3(512 + 384), dim3(256), 0, stream>>>(x, w, planes, bsw);
        dim3 grid(64, 4, B_);
        ring_mfma<<<grid, dim3(256), 0, stream>>>(planes, bsw, out);
    } else {
        dim3 grid(16, O_ / FOC, B_);
        ring_fb<<<grid, dim3(256), 0, stream>>>(x, w, out);
    }
}